// Round 1
// baseline (110.448 us; speedup 1.0000x reference)
//
#include <hip/hip_runtime.h>

// CompressK: ragged strided chunk gather + mean-pool.
//   k:          [total_tokens, H=4, D=128] f32
//   cu_seqlens: [B+1] int32
//   kernel_size, kernel_stride: scalar int32 (device, 1-elem arrays)
// out = concat( compressed_k [N, H, D] f32 flat,  cu_seqlens_compressed [B+1] as f32 )

#define HD 512          // H*D = 4*128
#define HD4 (HD / 4)    // float4 columns per token row

// Single-thread metadata kernel: B is tiny (4). Computes chunk counts,
// prefix sums (cu_comp), writes total+prefix to workspace and the f32 tail
// of d_out. Runs every launch (ws is re-poisoned to 0xAA before each call).
__global__ void meta_kernel(const int* __restrict__ cu, int B,
                            const int* __restrict__ ks_p,
                            const int* __restrict__ kst_p,
                            int* __restrict__ meta,
                            float* __restrict__ out_tail) {
    if (threadIdx.x == 0 && blockIdx.x == 0) {
        int ks = ks_p[0];
        int kst = kst_p[0];
        int acc = 0;
        meta[1] = 0;            // cu_comp[0]
        out_tail[0] = 0.0f;
        for (int b = 0; b < B; ++b) {
            int len = cu[b + 1] - cu[b];
            int nc = (len >= ks) ? ((len - ks) / kst + 1) : 0;
            acc += nc;
            meta[2 + b] = acc;              // cu_comp[b+1]
            out_tail[b + 1] = (float)acc;
        }
        meta[0] = acc;          // total chunk count
    }
}

// One block (128 threads) per chunk, grid-stride loop so the grid can be an
// upper bound. Thread t owns float4 column t of the 512-float token row:
// lanes 0..63 read 16B each -> 1KB coalesced per wave per token row.
__global__ __launch_bounds__(128)
void pool_kernel(const float* __restrict__ k,
                 const int* __restrict__ cu,
                 const int* __restrict__ ks_p,
                 const int* __restrict__ kst_p,
                 const int* __restrict__ meta,
                 float* __restrict__ out, int B) {
    const int total = meta[0];
    const int ks = ks_p[0];
    const int kst = kst_p[0];
    const float inv = 1.0f / (float)ks;
    const int tid = threadIdx.x;   // 0..127

    for (int c = blockIdx.x; c < total; c += gridDim.x) {
        // locate sequence b with cu_comp[b] <= c < cu_comp[b+1]  (B=4: linear)
        int b = 0;
        while (b + 1 < B && meta[1 + b + 1] <= c) ++b;
        const int lc = c - meta[1 + b];
        const int start = cu[b] + lc * kst;

        const float4* __restrict__ src =
            (const float4*)k + (size_t)start * HD4 + tid;
        float4 acc = make_float4(0.f, 0.f, 0.f, 0.f);
        for (int t = 0; t < ks; ++t) {
            float4 v = src[(size_t)t * HD4];
            acc.x += v.x; acc.y += v.y; acc.z += v.z; acc.w += v.w;
        }
        acc.x *= inv; acc.y *= inv; acc.z *= inv; acc.w *= inv;
        ((float4*)out)[(size_t)c * HD4 + tid] = acc;
    }
}

extern "C" void kernel_launch(void* const* d_in, const int* in_sizes, int n_in,
                              void* d_out, int out_size, void* d_ws, size_t ws_size,
                              hipStream_t stream) {
    const float* k   = (const float*)d_in[0];
    const int*   cu  = (const int*)d_in[1];
    const int*   ksp = (const int*)d_in[2];
    const int*   kstp= (const int*)d_in[3];
    float* out = (float*)d_out;
    int*   meta = (int*)d_ws;

    const int B = in_sizes[1] - 1;                 // number of sequences
    float* out_tail = out + (out_size - (B + 1));  // cu_comp tail (as f32)

    meta_kernel<<<1, 64, 0, stream>>>(cu, B, ksp, kstp, meta, out_tail);

    // Upper bound on chunks: total_tokens (stride >= 1). Use 2048 blocks with
    // a grid-stride loop; for the actual data (2044 chunks) each block does
    // exactly one chunk.
    pool_kernel<<<2048, 128, 0, stream>>>(k, cu, ksp, kstp, meta, out, B);
}

// Round 4
// 101.115 us; speedup vs baseline: 1.0923x; 1.0923x over previous
//
#include <hip/hip_runtime.h>

// CompressK: ragged strided chunk gather + mean-pool, fused single kernel.
//   k:          [total_tokens, H=4, D=128] f32
//   cu_seqlens: [B+1] int32
//   kernel_size, kernel_stride: scalar int32 (device 1-elem arrays)
// out = concat( compressed_k [N, H, D] f32 flat, cu_seqlens_compressed [B+1] as f32 )

#define HD4 128   // (H*D)/4 = 512/4 float4 columns per token row

__global__ __launch_bounds__(256)
void compress_k_fused(const float* __restrict__ k,
                      const int* __restrict__ cu,
                      const int* __restrict__ ks_p,
                      const int* __restrict__ kst_p,
                      float* __restrict__ out,
                      int B, int out_size) {
    const int ks  = ks_p[0];
    const int kst = kst_p[0];
    const float inv = 1.0f / (float)ks;

    // Total chunk count (uniform scalar work, B is tiny).
    int total = 0;
    for (int b = 0; b < B; ++b) {
        int len = cu[b + 1] - cu[b];
        total += (len >= ks) ? ((len - ks) / kst + 1) : 0;
    }

    const int tid = threadIdx.x;

    // Block 0 writes the cu_seqlens_compressed tail (as f32, harness reads f32).
    if (blockIdx.x == 0 && tid <= B) {
        int acc = 0;
        for (int b = 0; b < tid; ++b) {
            int len = cu[b + 1] - cu[b];
            acc += (len >= ks) ? ((len - ks) / kst + 1) : 0;
        }
        out[(size_t)out_size - (B + 1) + tid] = (float)acc;
    }

    const int col  = tid & (HD4 - 1);   // float4 column 0..127
    const int half = tid >> 7;          // row-half 0 or 1
    __shared__ float4 red[HD4];

    // Bijective XCD swizzle: gridDim.x is a multiple of 8 (launcher guarantees),
    // so consecutive chunks (which share ks-kst overlapping rows) map to the
    // same XCD's L2.
    const int nwg = gridDim.x;
    const int cpx = nwg >> 3;
    const int swz = (blockIdx.x & 7) * cpx + (blockIdx.x >> 3);

    for (int c = swz; c < total; c += nwg) {
        // Locate sequence b and local chunk index (uniform, B small).
        int b = 0, pre = 0;
        for (;;) {
            int len = cu[b + 1] - cu[b];
            int nc = (len >= ks) ? ((len - ks) / kst + 1) : 0;
            if (c < pre + nc) break;
            pre += nc; ++b;
        }
        const int start = cu[b] + (c - pre) * kst;

        // This half's row range: [r0, r1)
        const int r0 = half ? (ks >> 1) : 0;
        const int r1 = half ? ks : (ks >> 1);

        const float4* __restrict__ src =
            (const float4*)k + (size_t)(start + r0) * HD4 + col;
        float4 acc = make_float4(0.f, 0.f, 0.f, 0.f);
        #pragma unroll 4
        for (int t = r0; t < r1; ++t) {
            float4 v = *src;
            src += HD4;
            acc.x += v.x; acc.y += v.y; acc.z += v.z; acc.w += v.w;
        }

        if (half) red[col] = acc;
        __syncthreads();
        if (!half) {
            float4 o = red[col];
            o.x = (acc.x + o.x) * inv;
            o.y = (acc.y + o.y) * inv;
            o.z = (acc.z + o.z) * inv;
            o.w = (acc.w + o.w) * inv;
            ((float4*)out)[(size_t)c * HD4 + col] = o;
        }
        __syncthreads();   // red reused next grid-stride iteration
    }
}

extern "C" void kernel_launch(void* const* d_in, const int* in_sizes, int n_in,
                              void* d_out, int out_size, void* d_ws, size_t ws_size,
                              hipStream_t stream) {
    const float* k    = (const float*)d_in[0];
    const int*   cu   = (const int*)d_in[1];
    const int*   ksp  = (const int*)d_in[2];
    const int*   kstp = (const int*)d_in[3];
    float* out = (float*)d_out;

    const int B = in_sizes[1] - 1;

    // 2048 blocks (multiple of 8 for the XCD swizzle) x 4 waves = 32 waves/CU.
    // Grid-stride loop covers any chunk count beyond 2048.
    compress_k_fused<<<2048, 256, 0, stream>>>(k, cu, ksp, kstp, out, B, out_size);
}